// Round 1
// baseline (80.013 us; speedup 1.0000x reference)
//
#include <hip/hip_runtime.h>
#include <math.h>

// Problem constants (from reference)
#define P_TOTAL 10000
#define G_TOTAL 6400
#define C_CLS   18
#define NCHUNK  16
#define NG      (G_TOTAL / NCHUNK)   // 400 gaussians per chunk
#define REC_DW  40                   // record stride in dwords (160 B, 16B-aligned)

// Record layout (dwords):
// [0..3]   int4:  minx, miny, minz, 2*r          (voxel box, unsigned-range test)
// [4..7]   float: mux, muy, muz, opacity
// [8..11]  float: cxx, cyy, czz, cxy
// [12..13] float: cyz, cxz
// [16..33] float: sem[18]
// rest pad

__global__ void la_prep(const float* __restrict__ means3D,
                        const float* __restrict__ opacities,
                        const float* __restrict__ semantics,
                        const float* __restrict__ scales,
                        const float* __restrict__ cov3D,
                        float* __restrict__ rec) {
    int g = blockIdx.x * blockDim.x + threadIdx.x;
    if (g >= G_TOTAL) return;
    float mx = means3D[g * 3 + 0];
    float my = means3D[g * 3 + 1];
    float mz = means3D[g * 3 + 2];
    float sx = scales[g * 3 + 0];
    float sy = scales[g * 3 + 1];
    float sz = scales[g * 3 + 2];
    // (mu - PC_MIN)/0.5 == (mu - PC_MIN)*2 exactly (division by power of 2)
    int mix = (int)((mx + 50.0f) * 2.0f);
    int miy = (int)((my + 50.0f) * 2.0f);
    int miz = (int)((mz + 5.0f) * 2.0f);
    // radii = ceil(max(s)*3.0/0.5): *3.0 rounds, /0.5 exact
    int r = (int)ceilf((fmaxf(fmaxf(sx, sy), sz) * 3.0f) * 2.0f);
    float* o = rec + (size_t)g * REC_DW;
    int*   oi = (int*)o;
    oi[0] = mix - r;
    oi[1] = miy - r;
    oi[2] = miz - r;
    oi[3] = 2 * r;
    o[4] = mx; o[5] = my; o[6] = mz; o[7] = opacities[g];
    const float* cv = cov3D + (size_t)g * 9;
    o[8]  = cv[0];  // xx
    o[9]  = cv[4];  // yy
    o[10] = cv[8];  // zz
    o[11] = cv[1];  // xy
    o[12] = cv[5];  // yz
    o[13] = cv[2];  // xz
    o[14] = 0.0f; o[15] = 0.0f;
    const float* s = semantics + (size_t)g * C_CLS;
#pragma unroll
    for (int c = 0; c < C_CLS; ++c) o[16 + c] = s[c];
}

template <bool ATOMIC>
__global__ void la_agg(const float* __restrict__ pts,
                       const float* __restrict__ rec,
                       float* __restrict__ part_or_out) {
    __shared__ int4 sbox[NG];
    const int gc = blockIdx.y;                       // gaussian chunk
    const int pt = blockIdx.x * blockDim.x + threadIdx.x;  // point index
    const int gbase = gc * NG;

    // stage this chunk's voxel boxes into LDS
    for (int i = threadIdx.x; i < NG; i += blockDim.x) {
        sbox[i] = *(const int4*)(rec + (size_t)(gbase + i) * REC_DW);
    }
    __syncthreads();

    const bool valid = (pt < P_TOTAL);
    float px = 0.f, py = 0.f, pz = 0.f;
    int pix = 0x7f000000, piy = 0x7f000000, piz = 0x7f000000;  // fails all boxes
    if (valid) {
        px = pts[pt * 3 + 0];
        py = pts[pt * 3 + 1];
        pz = pts[pt * 3 + 2];
        pix = (int)((px + 50.0f) * 2.0f);
        piy = (int)((py + 50.0f) * 2.0f);
        piz = (int)((pz + 5.0f) * 2.0f);
    }

    float acc[C_CLS];
#pragma unroll
    for (int c = 0; c < C_CLS; ++c) acc[c] = 0.0f;

    for (int i = 0; i < NG; ++i) {
        int4 b = sbox[i];   // broadcast ds_read_b128
        unsigned ux = (unsigned)(pix - b.x);
        unsigned uy = (unsigned)(piy - b.y);
        unsigned uz = (unsigned)(piz - b.z);
        unsigned w  = (unsigned)b.w;
        if (ux <= w && uy <= w && uz <= w) {
            const float* o = rec + (size_t)(gbase + i) * REC_DW;
            float4 g0 = *(const float4*)(o + 4);   // mu, op
            float4 g1 = *(const float4*)(o + 8);   // cxx cyy czz cxy
            float2 g2 = *(const float2*)(o + 12);  // cyz cxz
            float dx = px - g0.x, dy = py - g0.y, dz = pz - g0.z;
            float pw = -0.5f * (g1.x * dx * dx + g1.y * dy * dy + g1.z * dz * dz)
                       - g1.w * dx * dy - g2.x * dy * dz - g2.y * dx * dz;
            float wgt = __expf(pw) * g0.w;
#pragma unroll
            for (int c = 0; c < C_CLS; ++c) acc[c] = fmaf(wgt, o[16 + c], acc[c]);
        }
    }

    if (valid) {
        if (ATOMIC) {
            float* dst = part_or_out + (size_t)pt * C_CLS;
#pragma unroll
            for (int c = 0; c < C_CLS; ++c)
                if (acc[c] != 0.0f) atomicAdd(dst + c, acc[c]);
        } else {
            float* dst = part_or_out + ((size_t)gc * P_TOTAL + pt) * C_CLS;
#pragma unroll
            for (int c = 0; c < C_CLS; ++c) dst[c] = acc[c];
        }
    }
}

__global__ void la_reduce(const float* __restrict__ part, float* __restrict__ out) {
    int o = blockIdx.x * blockDim.x + threadIdx.x;
    if (o >= P_TOTAL * C_CLS) return;
    float s = 0.0f;
#pragma unroll
    for (int k = 0; k < NCHUNK; ++k)
        s += part[(size_t)k * (P_TOTAL * C_CLS) + o];
    out[o] = s;
}

extern "C" void kernel_launch(void* const* d_in, const int* in_sizes, int n_in,
                              void* d_out, int out_size, void* d_ws, size_t ws_size,
                              hipStream_t stream) {
    const float* pts      = (const float*)d_in[0];
    const float* means3D  = (const float*)d_in[1];
    const float* opac     = (const float*)d_in[2];
    const float* sem      = (const float*)d_in[3];
    const float* scales   = (const float*)d_in[4];
    const float* cov3D    = (const float*)d_in[5];
    float* out = (float*)d_out;

    float* rec  = (float*)d_ws;
    const size_t rec_bytes  = (size_t)G_TOTAL * REC_DW * sizeof(float);
    const size_t part_bytes = (size_t)NCHUNK * P_TOTAL * C_CLS * sizeof(float);
    float* part = rec + (size_t)G_TOTAL * REC_DW;

    la_prep<<<(G_TOTAL + 255) / 256, 256, 0, stream>>>(means3D, opac, sem, scales, cov3D, rec);

    dim3 grid((P_TOTAL + 255) / 256, NCHUNK);
    if (ws_size >= rec_bytes + part_bytes) {
        la_agg<false><<<grid, 256, 0, stream>>>(pts, rec, part);
        la_reduce<<<(P_TOTAL * C_CLS + 255) / 256, 256, 0, stream>>>(part, out);
    } else {
        hipMemsetAsync(d_out, 0, (size_t)out_size * sizeof(float), stream);
        la_agg<true><<<grid, 256, 0, stream>>>(pts, rec, out);
    }
}

// Round 2
// 36.494 us; speedup vs baseline: 2.1925x; 2.1925x over previous
//
#include <hip/hip_runtime.h>
#include <math.h>

// Problem constants (from reference)
#define P_TOTAL 10000
#define G_TOTAL 6400
#define C_CLS   18
#define REC_DW  40        // gaussian record stride in dwords (160 B)
#define CS_SH   3         // cell = 8 voxels = 4 m
#define NCX     25
#define NCY     25
#define NCELL   (NCX * NCY)
#define MAXE    256       // entry slots per cell (mean fill ~50)
#define TPP     16        // threads per point in gather

// Record layout (dwords):
// [4..7]   float: mux, muy, muz, opacity
// [8..11]  float: cxx, cyy, czz, cxy
// [12..13] float: cyz, cxz
// [16..33] float: sem[18]

__global__ void la_prep(const float* __restrict__ means3D,
                        const float* __restrict__ opacities,
                        const float* __restrict__ semantics,
                        const float* __restrict__ scales,
                        const float* __restrict__ cov3D,
                        float* __restrict__ rec,
                        int* __restrict__ counts,
                        int4* __restrict__ entries) {
    int g = blockIdx.x * blockDim.x + threadIdx.x;
    if (g >= G_TOTAL) return;
    float mx = means3D[g * 3 + 0];
    float my = means3D[g * 3 + 1];
    float mz = means3D[g * 3 + 2];
    float sx = scales[g * 3 + 0];
    float sy = scales[g * 3 + 1];
    float sz = scales[g * 3 + 2];
    // (mu - PC_MIN)/0.5 == (mu - PC_MIN)*2 exactly
    int mix = (int)((mx + 50.0f) * 2.0f);
    int miy = (int)((my + 50.0f) * 2.0f);
    int miz = (int)((mz + 5.0f) * 2.0f);
    // radii = ceil(max(s)*3.0/0.5): *3.0 rounds, *2 exact
    int r = (int)ceilf((fmaxf(fmaxf(sx, sy), sz) * 3.0f) * 2.0f);
    int w = 2 * r;

    float* o = rec + (size_t)g * REC_DW;
    o[4] = mx; o[5] = my; o[6] = mz; o[7] = opacities[g];
    const float* cv = cov3D + (size_t)g * 9;
    o[8]  = cv[0];  // xx
    o[9]  = cv[4];  // yy
    o[10] = cv[8];  // zz
    o[11] = cv[1];  // xy
    o[12] = cv[5];  // yz
    o[13] = cv[2];  // xz
    const float* s = semantics + (size_t)g * C_CLS;
#pragma unroll
    for (int c = 0; c < C_CLS; ++c) o[16 + c] = s[c];

    // scatter packed box entry into every overlapped cell
    int minx = mix - r, miny = miy - r, minz = miz - r;
    int cx0 = max(minx, 0) >> CS_SH;
    int cx1 = min(minx + w, 199) >> CS_SH;
    int cy0 = max(miny, 0) >> CS_SH;
    int cy1 = min(miny + w, 199) >> CS_SH;
    int4 e = make_int4(minx, miny, minz, (w << 16) | g);
    for (int cy = cy0; cy <= cy1; ++cy) {
        for (int cx = cx0; cx <= cx1; ++cx) {
            int cell = cy * NCX + cx;
            int slot = atomicAdd(&counts[cell], 1);
            if (slot < MAXE) entries[(size_t)cell * MAXE + slot] = e;
        }
    }
}

__global__ void la_gather(const float* __restrict__ pts,
                          const float* __restrict__ rec,
                          const int* __restrict__ counts,
                          const int4* __restrict__ entries,
                          float* __restrict__ out) {
    const int grp  = threadIdx.x >> 4;          // 16 point-groups per block
    const int lane = threadIdx.x & 15;
    const int pt = blockIdx.x * 16 + grp;       // 625 blocks * 16 = 10000
    if (pt >= P_TOTAL) return;

    float px = pts[pt * 3 + 0];
    float py = pts[pt * 3 + 1];
    float pz = pts[pt * 3 + 2];
    int pix = (int)((px + 50.0f) * 2.0f);
    int piy = (int)((py + 50.0f) * 2.0f);
    int piz = (int)((pz + 5.0f) * 2.0f);

    int cell = (piy >> CS_SH) * NCX + (pix >> CS_SH);
    int cnt = min(counts[cell], MAXE);
    const int4* eb = entries + (size_t)cell * MAXE;

    float acc[C_CLS];
#pragma unroll
    for (int c = 0; c < C_CLS; ++c) acc[c] = 0.0f;

#pragma unroll 2
    for (int i = lane; i < cnt; i += TPP) {
        int4 b = eb[i];                          // coalesced 16B within cell
        unsigned w = ((unsigned)b.w) >> 16;
        unsigned ux = (unsigned)(pix - b.x);
        unsigned uy = (unsigned)(piy - b.y);
        unsigned uz = (unsigned)(piz - b.z);
        if (ux <= w && uy <= w && uz <= w) {
            int gid = b.w & 0xffff;
            const float* o = rec + (size_t)gid * REC_DW;
            float4 g0 = *(const float4*)(o + 4);   // mu, op
            float4 g1 = *(const float4*)(o + 8);   // cxx cyy czz cxy
            float2 g2 = *(const float2*)(o + 12);  // cyz cxz
            float dx = px - g0.x, dy = py - g0.y, dz = pz - g0.z;
            float pw = -0.5f * (g1.x * dx * dx + g1.y * dy * dy + g1.z * dz * dz)
                       - g1.w * dx * dy - g2.x * dy * dz - g2.y * dx * dz;
            float wgt = __expf(pw) * g0.w;
            float4 s0 = *(const float4*)(o + 16);
            float4 s1 = *(const float4*)(o + 20);
            float4 s2 = *(const float4*)(o + 24);
            float4 s3 = *(const float4*)(o + 28);
            float2 s4 = *(const float2*)(o + 32);
            acc[0]  = fmaf(wgt, s0.x, acc[0]);  acc[1]  = fmaf(wgt, s0.y, acc[1]);
            acc[2]  = fmaf(wgt, s0.z, acc[2]);  acc[3]  = fmaf(wgt, s0.w, acc[3]);
            acc[4]  = fmaf(wgt, s1.x, acc[4]);  acc[5]  = fmaf(wgt, s1.y, acc[5]);
            acc[6]  = fmaf(wgt, s1.z, acc[6]);  acc[7]  = fmaf(wgt, s1.w, acc[7]);
            acc[8]  = fmaf(wgt, s2.x, acc[8]);  acc[9]  = fmaf(wgt, s2.y, acc[9]);
            acc[10] = fmaf(wgt, s2.z, acc[10]); acc[11] = fmaf(wgt, s2.w, acc[11]);
            acc[12] = fmaf(wgt, s3.x, acc[12]); acc[13] = fmaf(wgt, s3.y, acc[13]);
            acc[14] = fmaf(wgt, s3.z, acc[14]); acc[15] = fmaf(wgt, s3.w, acc[15]);
            acc[16] = fmaf(wgt, s4.x, acc[16]); acc[17] = fmaf(wgt, s4.y, acc[17]);
        }
    }

    // reduce across the 16 lanes of this point-group
#pragma unroll
    for (int m = 8; m >= 1; m >>= 1) {
#pragma unroll
        for (int c = 0; c < C_CLS; ++c)
            acc[c] += __shfl_xor(acc[c], m, 64);
    }

    if (lane == 0) {
        float* dst = out + (size_t)pt * C_CLS;
#pragma unroll
        for (int c = 0; c < C_CLS; ++c) dst[c] = acc[c];
    }
}

extern "C" void kernel_launch(void* const* d_in, const int* in_sizes, int n_in,
                              void* d_out, int out_size, void* d_ws, size_t ws_size,
                              hipStream_t stream) {
    const float* pts      = (const float*)d_in[0];
    const float* means3D  = (const float*)d_in[1];
    const float* opac     = (const float*)d_in[2];
    const float* sem      = (const float*)d_in[3];
    const float* scales   = (const float*)d_in[4];
    const float* cov3D    = (const float*)d_in[5];
    float* out = (float*)d_out;

    char* ws = (char*)d_ws;
    float* rec      = (float*)ws;                              // 1,024,000 B
    int*   counts   = (int*)(ws + 1024000);                    // 2,500 B
    int4*  entries  = (int4*)(ws + 1024000 + 4096);            // 2,560,000 B

    hipMemsetAsync(counts, 0, NCELL * sizeof(int), stream);
    la_prep<<<(G_TOTAL + 255) / 256, 256, 0, stream>>>(means3D, opac, sem, scales,
                                                       cov3D, rec, counts, entries);
    la_gather<<<(P_TOTAL + 15) / 16, 256, 0, stream>>>(pts, rec, counts, entries, out);
}

// Round 3
// 34.634 us; speedup vs baseline: 2.3102x; 1.0537x over previous
//
#include <hip/hip_runtime.h>
#include <math.h>

// Problem constants (from reference)
#define P_TOTAL 10000
#define G_TOTAL 6400
#define C_CLS   18
#define REC_DW  40        // gaussian record stride in dwords (160 B)
#define CS_SH   3         // cell = 8 voxels = 4 m
#define NCX     25
#define NCY     25
#define NCELL   (NCX * NCY)
#define MAXE    256       // entry slots per cell (mean fill ~50)
#define TPP     16        // threads per point in gather

// Record layout (dwords):
// [4..7]   float: mux, muy, muz, opacity
// [8..11]  float: cxx, cyy, czz, cxy
// [12..13] float: cyz, cxz
// [16..33] float: sem[18]

__global__ void la_zero(int* __restrict__ counts) {
    int i = threadIdx.x + blockIdx.x * blockDim.x;
    if (i < NCELL) counts[i] = 0;
}

__global__ void la_prep(const float* __restrict__ means3D,
                        const float* __restrict__ opacities,
                        const float* __restrict__ semantics,
                        const float* __restrict__ scales,
                        const float* __restrict__ cov3D,
                        float* __restrict__ rec,
                        int* __restrict__ counts,
                        int4* __restrict__ entries) {
    int g = blockIdx.x * blockDim.x + threadIdx.x;
    if (g >= G_TOTAL) return;
    float mx = means3D[g * 3 + 0];
    float my = means3D[g * 3 + 1];
    float mz = means3D[g * 3 + 2];
    float sx = scales[g * 3 + 0];
    float sy = scales[g * 3 + 1];
    float sz = scales[g * 3 + 2];
    // (mu - PC_MIN)/0.5 == (mu - PC_MIN)*2 exactly
    int mix = (int)((mx + 50.0f) * 2.0f);
    int miy = (int)((my + 50.0f) * 2.0f);
    int miz = (int)((mz + 5.0f) * 2.0f);
    // radii = ceil(max(s)*3.0/0.5): *3.0 rounds, *2 exact
    int r = (int)ceilf((fmaxf(fmaxf(sx, sy), sz) * 3.0f) * 2.0f);
    int w = 2 * r;

    float* o = rec + (size_t)g * REC_DW;
    o[4] = mx; o[5] = my; o[6] = mz; o[7] = opacities[g];
    const float* cv = cov3D + (size_t)g * 9;
    o[8]  = cv[0];  // xx
    o[9]  = cv[4];  // yy
    o[10] = cv[8];  // zz
    o[11] = cv[1];  // xy
    o[12] = cv[5];  // yz
    o[13] = cv[2];  // xz
    const float* s = semantics + (size_t)g * C_CLS;
#pragma unroll
    for (int c = 0; c < C_CLS; ++c) o[16 + c] = s[c];

    // scatter packed box entry into every overlapped cell
    int minx = mix - r, miny = miy - r, minz = miz - r;
    int cx0 = max(minx, 0) >> CS_SH;
    int cx1 = min(minx + w, 199) >> CS_SH;
    int cy0 = max(miny, 0) >> CS_SH;
    int cy1 = min(miny + w, 199) >> CS_SH;
    int4 e = make_int4(minx, miny, minz, (w << 16) | g);
    for (int cy = cy0; cy <= cy1; ++cy) {
        for (int cx = cx0; cx <= cx1; ++cx) {
            int cell = cy * NCX + cx;
            int slot = atomicAdd(&counts[cell], 1);
            if (slot < MAXE) entries[(size_t)cell * MAXE + slot] = e;
        }
    }
}

__global__ void la_gather(const float* __restrict__ pts,
                          const float* __restrict__ rec,
                          const int* __restrict__ counts,
                          const int4* __restrict__ entries,
                          float* __restrict__ out) {
    const int grp  = threadIdx.x >> 4;          // 16 point-groups per block
    const int lane = threadIdx.x & 15;
    const int pt = blockIdx.x * 16 + grp;       // 625 blocks * 16 = 10000
    if (pt >= P_TOTAL) return;

    float px = pts[pt * 3 + 0];
    float py = pts[pt * 3 + 1];
    float pz = pts[pt * 3 + 2];
    int pix = (int)((px + 50.0f) * 2.0f);
    int piy = (int)((py + 50.0f) * 2.0f);
    int piz = (int)((pz + 5.0f) * 2.0f);

    int cell = (piy >> CS_SH) * NCX + (pix >> CS_SH);
    int cnt = min(counts[cell], MAXE);
    const int4* eb = entries + (size_t)cell * MAXE;

    float acc[C_CLS];
#pragma unroll
    for (int c = 0; c < C_CLS; ++c) acc[c] = 0.0f;

#pragma unroll 2
    for (int i = lane; i < cnt; i += TPP) {
        int4 b = eb[i];                          // coalesced 16B within cell
        unsigned w = ((unsigned)b.w) >> 16;
        unsigned ux = (unsigned)(pix - b.x);
        unsigned uy = (unsigned)(piy - b.y);
        unsigned uz = (unsigned)(piz - b.z);
        if (ux <= w && uy <= w && uz <= w) {
            int gid = b.w & 0xffff;
            const float* o = rec + (size_t)gid * REC_DW;
            float4 g0 = *(const float4*)(o + 4);   // mu, op
            float4 g1 = *(const float4*)(o + 8);   // cxx cyy czz cxy
            float2 g2 = *(const float2*)(o + 12);  // cyz cxz
            float dx = px - g0.x, dy = py - g0.y, dz = pz - g0.z;
            float pw = -0.5f * (g1.x * dx * dx + g1.y * dy * dy + g1.z * dz * dz)
                       - g1.w * dx * dy - g2.x * dy * dz - g2.y * dx * dz;
            float wgt = __expf(pw) * g0.w;
            float4 s0 = *(const float4*)(o + 16);
            float4 s1 = *(const float4*)(o + 20);
            float4 s2 = *(const float4*)(o + 24);
            float4 s3 = *(const float4*)(o + 28);
            float2 s4 = *(const float2*)(o + 32);
            acc[0]  = fmaf(wgt, s0.x, acc[0]);  acc[1]  = fmaf(wgt, s0.y, acc[1]);
            acc[2]  = fmaf(wgt, s0.z, acc[2]);  acc[3]  = fmaf(wgt, s0.w, acc[3]);
            acc[4]  = fmaf(wgt, s1.x, acc[4]);  acc[5]  = fmaf(wgt, s1.y, acc[5]);
            acc[6]  = fmaf(wgt, s1.z, acc[6]);  acc[7]  = fmaf(wgt, s1.w, acc[7]);
            acc[8]  = fmaf(wgt, s2.x, acc[8]);  acc[9]  = fmaf(wgt, s2.y, acc[9]);
            acc[10] = fmaf(wgt, s2.z, acc[10]); acc[11] = fmaf(wgt, s2.w, acc[11]);
            acc[12] = fmaf(wgt, s3.x, acc[12]); acc[13] = fmaf(wgt, s3.y, acc[13]);
            acc[14] = fmaf(wgt, s3.z, acc[14]); acc[15] = fmaf(wgt, s3.w, acc[15]);
            acc[16] = fmaf(wgt, s4.x, acc[16]); acc[17] = fmaf(wgt, s4.y, acc[17]);
        }
    }

    // reduce across the 16 lanes of this point-group
#pragma unroll
    for (int m = 8; m >= 1; m >>= 1) {
#pragma unroll
        for (int c = 0; c < C_CLS; ++c)
            acc[c] += __shfl_xor(acc[c], m, 64);
    }

    if (lane == 0) {
        float* dst = out + (size_t)pt * C_CLS;
#pragma unroll
        for (int c = 0; c < C_CLS; ++c) dst[c] = acc[c];
    }
}

extern "C" void kernel_launch(void* const* d_in, const int* in_sizes, int n_in,
                              void* d_out, int out_size, void* d_ws, size_t ws_size,
                              hipStream_t stream) {
    const float* pts      = (const float*)d_in[0];
    const float* means3D  = (const float*)d_in[1];
    const float* opac     = (const float*)d_in[2];
    const float* sem      = (const float*)d_in[3];
    const float* scales   = (const float*)d_in[4];
    const float* cov3D    = (const float*)d_in[5];
    float* out = (float*)d_out;

    char* ws = (char*)d_ws;
    float* rec      = (float*)ws;                              // 1,024,000 B
    int*   counts   = (int*)(ws + 1024000);                    // 2,500 B
    int4*  entries  = (int4*)(ws + 1024000 + 4096);            // 2,560,000 B

    la_zero<<<(NCELL + 255) / 256, 256, 0, stream>>>(counts);
    la_prep<<<(G_TOTAL + 255) / 256, 256, 0, stream>>>(means3D, opac, sem, scales,
                                                       cov3D, rec, counts, entries);
    la_gather<<<(P_TOTAL + 15) / 16, 256, 0, stream>>>(pts, rec, counts, entries, out);
}